// Round 5
// baseline (300.918 us; speedup 1.0000x reference)
//
#include <hip/hip_runtime.h>
#include <stdint.h>

typedef uint16_t u16;
typedef _Float16 f16;
typedef __attribute__((ext_vector_type(8)))  f16      f16x8;
typedef __attribute__((ext_vector_type(2)))  __fp16   h16x2;   // native type of cvt_pkrtz
typedef __attribute__((ext_vector_type(8)))  uint16_t u16x8;
typedef __attribute__((ext_vector_type(4)))  uint16_t u16x4;
typedef __attribute__((ext_vector_type(4)))  uint32_t u32x4;
typedef __attribute__((ext_vector_type(4)))  float    f32x4;
typedef __attribute__((ext_vector_type(16))) float    f32x16;

#define LOG2E 1.44269504088896340736f
#define MFMA16F(a, b, c) __builtin_amdgcn_mfma_f32_16x16x32_f16((a), (b), (c), 0, 0, 0)
#define MFMA32F(a, b, c) __builtin_amdgcn_mfma_f32_32x32x16_f16((a), (b), (c), 0, 0, 0)

__device__ __forceinline__ u16 f2h(float f) {
  f16 h = (f16)f;
  return __builtin_bit_cast(u16, h);
}
__device__ __forceinline__ uint32_t pk2(float a, float b) {  // packed f32->f16 (RTZ)
  h16x2 h = __builtin_amdgcn_cvt_pkrtz(a, b);
  return __builtin_bit_cast(uint32_t, h);
}

// LDS tiles: [rows][64 f16] = 8 chunks of 16B per row, chunk XOR-swizzled by row&7.
__device__ __forceinline__ f16x8 ldsFrag(const u16* base, int row, int chunk) {
  const u16* p = base + row * 64 + ((chunk ^ (row & 7)) << 3);
  u16x8 raw = *(const u16x8*)p;
  return __builtin_bit_cast(f16x8, raw);
}
__device__ __forceinline__ void ldsPut(u16* base, int row, int logicalChunk, u16x8 v) {
  u16* p = base + row * 64 + ((logicalChunk ^ (row & 7)) << 3);
  *(u16x8*)p = v;
}

// async global->LDS DMA, 16B/lane; LDS dest = wave-uniform base + lane*16.
__device__ __forceinline__ void dma16(const u16* g, u16* l) {
  __builtin_amdgcn_global_load_lds(
      (const __attribute__((address_space(1))) uint32_t*)g,
      (__attribute__((address_space(3))) uint32_t*)l, 16, 0, 0);
}

// ---------------- kernel 0: pack weights ----------------
// Wt[n][k] f16 (n<64: Wf*log2e, n<128: Wg, else Wh), biasc[n] fp32 (bf*log2e).
__global__ __launch_bounds__(256) void pack_weights2(
    const float* __restrict__ Wf, const float* __restrict__ Wg,
    const float* __restrict__ Wh, const float* __restrict__ bfv,
    const float* __restrict__ bgv, const float* __restrict__ bhv,
    u16* __restrict__ Wt, float* __restrict__ biasc) {
  __shared__ u16 T[64 * 64];       // [k][n]
  const int nt = blockIdx.x >> 3;  // 0..9
  const int kt = blockIdx.x & 7;   // 0..7
  const int n0 = nt * 64, k0 = kt * 64;
  const float* src; int stride, cbase; float scale = 1.0f;
  if (nt == 0)      { src = Wf; stride = 64;  cbase = 0;        scale = LOG2E; }
  else if (nt == 1) { src = Wg; stride = 64;  cbase = 0; }
  else              { src = Wh; stride = 512; cbase = n0 - 128; }
  const int t = threadIdx.x;
  const int cl = (t & 15) * 4, r0 = t >> 4;
#pragma unroll
  for (int j = 0; j < 4; ++j) {
    int r = r0 + j * 16;
    f32x4 v = *(const f32x4*)(src + (size_t)(k0 + r) * stride + cbase + cl);
    u16x4 o;
#pragma unroll
    for (int i = 0; i < 4; ++i) o[i] = f2h(v[i] * scale);
    *(u16x4*)(T + r * 64 + cl) = o;
  }
  __syncthreads();
  const int n = t >> 2, kq = (t & 3) * 16;
  u16x8 a, b2;
#pragma unroll
  for (int i = 0; i < 8; ++i) { a[i] = T[(kq + i) * 64 + n]; b2[i] = T[(kq + 8 + i) * 64 + n]; }
  *(u16x8*)(Wt + (size_t)(n0 + n) * 512 + k0 + kq) = a;
  *(u16x8*)(Wt + (size_t)(n0 + n) * 512 + k0 + kq + 8) = b2;
  if (kt == 0 && t < 64) {
    float bv = (nt == 0) ? bfv[t] * LOG2E : (nt == 1) ? bgv[t] : bhv[cbase + t];
    biasc[n0 + t] = bv;
  }
}

// ---------------- kernel 1: projection GEMM (M=64, N=128, 1280 blocks) -------
__global__ __launch_bounds__(256, 4) void proj_gemm2(
    const float* __restrict__ x, const u16* __restrict__ Wt,
    const float* __restrict__ biasc,
    u16* __restrict__ fo, u16* __restrict__ go, u16* __restrict__ ht) {
  __shared__ u16 smem[64 * 64 + 128 * 64];   // 24 KB: A | B, reused as T
  u16* lds_a = smem;
  u16* lds_b = smem + 64 * 64;
  const int t = threadIdx.x, lane = t & 63, w = t >> 6;
  const int m0 = blockIdx.x * 64, n0 = blockIdx.y * 128;
  const int l15 = lane & 15, l4 = lane >> 4;
  const int sr = t >> 3, sc = t & 7;
  const int dmarow = lane >> 3, dmachunk = (lane & 7) ^ (lane >> 3);

  f32x4 acc[4][2];
#pragma unroll
  for (int i = 0; i < 4; ++i)
#pragma unroll
    for (int j = 0; j < 2; ++j) acc[i][j] = (f32x4)(0.f);

  for (int kb = 0; kb < 8; ++kb) {
    const int k0 = kb * 64;
    if (kb) __syncthreads();
#pragma unroll
    for (int p = 0; p < 2; ++p) {            // stage A: x fp32 -> f16 (64x64)
      int rr = p * 32 + sr;
      const float* s = x + (size_t)(m0 + rr) * 512 + k0 + sc * 8;
      f32x4 a0 = *(const f32x4*)s;
      f32x4 a1 = *(const f32x4*)(s + 4);
      u16x8 v;
#pragma unroll
      for (int i = 0; i < 4; ++i) { v[i] = f2h(a0[i]); v[4 + i] = f2h(a1[i]); }
      ldsPut(lds_a, rr, sc, v);
    }
#pragma unroll
    for (int ii = 0; ii < 4; ++ii) {         // stage B: Wt via DMA (128x64)
      int rw = w * 32 + ii * 8;
      const u16* src = Wt + (size_t)(n0 + rw + dmarow) * 512 + k0 + dmachunk * 8;
      dma16(src, lds_b + rw * 64);
    }
    __syncthreads();
#pragma unroll
    for (int ks = 0; ks < 2; ++ks) {
      const int chunk = ks * 4 + l4;
      f16x8 af[4], bq[2];
#pragma unroll
      for (int mt = 0; mt < 4; ++mt) af[mt] = ldsFrag(lds_a, mt * 16 + l15, chunk);
#pragma unroll
      for (int nt = 0; nt < 2; ++nt) bq[nt] = ldsFrag(lds_b, w * 32 + nt * 16 + l15, chunk);
#pragma unroll
      for (int mt = 0; mt < 4; ++mt)
#pragma unroll
        for (int nt = 0; nt < 2; ++nt) acc[mt][nt] = MFMA16F(af[mt], bq[nt], acc[mt][nt]);
    }
  }

  if (n0 >= 128) {
    // ---- h path: LDS-bounce transpose -> coalesced ht stores ----
    __syncthreads();
#pragma unroll
    for (int nt = 0; nt < 2; ++nt) {
      int nl = w * 32 + nt * 16 + l15;       // n within block (0..127)
      float bv = biasc[n0 + nl];
#pragma unroll
      for (int mt = 0; mt < 4; ++mt) {
        int mb = mt * 16 + (l4 << 2);
        f32x4 a = acc[mt][nt];
        u16x4 v;
#pragma unroll
        for (int r = 0; r < 4; ++r) v[r] = f2h(a[r] + bv);
        u16* dst = smem + nl * 64 + (((mb >> 3) ^ (nl & 7)) << 3) + (mb & 7);
        *(u16x4*)dst = v;
      }
    }
    __syncthreads();
    const int bb = m0 >> 12, posb = m0 & 4095;
    const int rr = t >> 1, half = t & 1;
    int vcol = n0 - 128 + rr;
#pragma unroll
    for (int j = 0; j < 4; ++j) {
      int ch = half * 4 + j;
      u16x8 v = *(const u16x8*)(smem + rr * 64 + ((ch ^ (rr & 7)) << 3));
      *(u16x8*)(ht + ((size_t)(bb * 512 + vcol) << 12) + posb + ch * 8) = v;
    }
  } else {
    // ---- f/g path ----
#pragma unroll
    for (int nt = 0; nt < 2; ++nt) {
      int n = w * 32 + nt * 16 + l15;
      float bv = biasc[n];
#pragma unroll
      for (int mt = 0; mt < 4; ++mt) {
        int mrow = m0 + mt * 16 + (l4 << 2);
        f32x4 a = acc[mt][nt];
        if (n < 64) {
#pragma unroll
          for (int r = 0; r < 4; ++r) fo[(size_t)(mrow + r) * 64 + n] = f2h(a[r] + bv);
        } else {
#pragma unroll
          for (int r = 0; r < 4; ++r) go[(size_t)(mrow + r) * 64 + (n - 64)] = f2h(a[r] + bv);
        }
      }
    }
  }
}

// ---------------- kernel 2: attention v4 — zero-barrier register-P ----------
// 1024 blocks x 4 waves. Block: Q=64 q x VC=128 c, all 4096 keys; wave w owns
// 32-key chunks at key0 = c*128 + w*32. S^T = g.f^T (mfma 32x32x16, f16);
// D row=key=(r&3)+8*(r>>2)+4*l5 re-shapes to PV A-operand (k=l5*8+j) via
// shfl_xor(32) pair exchange — P never touches LDS, no barriers in main loop.
// exp2(s-12) keeps P in f16 range (softmax shift-invariant). g/ht read direct
// from XCD-local L2 (slice swizzle i&15). O in regs; LDS reduction at end.
__global__ __launch_bounds__(256, 2) void attn4(
    const f16* __restrict__ fq, const f16* __restrict__ gk,
    const f16* __restrict__ ht, const float* __restrict__ x,
    const float* __restrict__ gamma_p, float* __restrict__ out) {
  __shared__ float lds_o[64 * 128];    // 32 KB O accumulator
  __shared__ float lds_l[4 * 64];

  const int i = blockIdx.x;            // 1024
  const int slice = i & 15;            // XCD x gets slices {x, x+8}
  const int b = slice >> 2, vq = slice & 3;
  const int qb = i >> 4;               // 0..63
  const int q0 = qb * 64, vc0 = vq * 128;

  const int t = threadIdx.x, lane = t & 63, w = t >> 6;
  const int l31 = lane & 31, l5 = lane >> 5;
  const float gamma = gamma_p[0];

  const f16* gbase = gk + (size_t)(b * 4096) * 64;
  const f16* hbase = ht + ((size_t)(b * 512 + vc0)) * 4096;

  // f B-frags (Sᵀ): 2 qt x 4 ks, pinned
  f16x8 fB[2][4];
#pragma unroll
  for (int qt = 0; qt < 2; ++qt)
#pragma unroll
    for (int ks = 0; ks < 4; ++ks)
      fB[qt][ks] = *(const f16x8*)(fq + (size_t)(b * 4096 + q0 + qt * 32 + l31) * 64 + ks * 16 + l5 * 8);

  f32x16 oacc[2][4];
#pragma unroll
  for (int qt = 0; qt < 2; ++qt)
#pragma unroll
    for (int ct = 0; ct < 4; ++ct) oacc[qt][ct] = (f32x16)(0.f);
  float lrun[2] = {0.f, 0.f};

  for (int c = 0; c < 32; ++c) {
    const int key0 = c * 128 + w * 32;
    // g A-frags (16B/lane, contiguous) and ht B-frags direct from L2
    f16x8 gA[4];
#pragma unroll
    for (int ks = 0; ks < 4; ++ks)
      gA[ks] = *(const f16x8*)(gbase + (size_t)(key0 + l31) * 64 + ks * 16 + l5 * 8);
    f16x8 hB[2][4];
#pragma unroll
    for (int s2 = 0; s2 < 2; ++s2)
#pragma unroll
      for (int ct = 0; ct < 4; ++ct)
        hB[s2][ct] = *(const f16x8*)(hbase + (size_t)(ct * 32 + l31) * 4096 + key0 + s2 * 16 + l5 * 8);

#pragma unroll
    for (int qt = 0; qt < 2; ++qt) {
      f32x16 s = (f32x16)(0.f);
#pragma unroll
      for (int ks = 0; ks < 4; ++ks) s = MFMA32F(gA[ks], fB[qt][ks], s);
      // p = exp2(S*log2e - 12)  (log2e folded into f; -12 keeps P in f16 range)
      float p[16];
#pragma unroll
      for (int r = 0; r < 16; ++r) p[r] = __builtin_amdgcn_exp2f(s[r] - 12.0f);
      float ps = 0.f;
#pragma unroll
      for (int r = 0; r < 16; ++r) ps += p[r];
      lrun[qt] += ps;
      // pack: G[g][d] = keys 8g+4*l5+{2d,2d+1}
      uint32_t G[4][2];
#pragma unroll
      for (int g = 0; g < 4; ++g) {
        G[g][0] = pk2(p[4 * g + 0], p[4 * g + 1]);
        G[g][1] = pk2(p[4 * g + 2], p[4 * g + 3]);
      }
      // PV steps: keys [key0+16*s2, +16); A-frag dwords [l5src=0 d0,d1, l5src=1 d0,d1]
#pragma unroll
      for (int s2 = 0; s2 < 2; ++s2) {
        uint32_t sA0 = (uint32_t)__shfl_xor((int)G[2 * s2 + 1][0], 32);
        uint32_t sA1 = (uint32_t)__shfl_xor((int)G[2 * s2 + 1][1], 32);
        uint32_t sB0 = (uint32_t)__shfl_xor((int)G[2 * s2][0], 32);
        uint32_t sB1 = (uint32_t)__shfl_xor((int)G[2 * s2][1], 32);
        u32x4 av;
        av[0] = l5 ? sA0 : G[2 * s2][0];
        av[1] = l5 ? sA1 : G[2 * s2][1];
        av[2] = l5 ? G[2 * s2 + 1][0] : sB0;
        av[3] = l5 ? G[2 * s2 + 1][1] : sB1;
        f16x8 aP = __builtin_bit_cast(f16x8, av);
#pragma unroll
        for (int ct = 0; ct < 4; ++ct)
          oacc[qt][ct] = MFMA32F(aP, hB[s2][ct], oacc[qt][ct]);
      }
    }
  }

  // ---- l reduction: pair lanes share q=l31; cross-wave via LDS ----
#pragma unroll
  for (int qt = 0; qt < 2; ++qt) lrun[qt] += __shfl_xor(lrun[qt], 32);
  if (l5 == 0) {
#pragma unroll
    for (int qt = 0; qt < 2; ++qt) lds_l[w * 64 + qt * 32 + l31] = lrun[qt];
  }

  // ---- O reduction across 4 key-quarter waves (serial rounds) ----
  for (int wv = 0; wv < 4; ++wv) {
    if (w == wv) {
#pragma unroll
      for (int qt = 0; qt < 2; ++qt)
#pragma unroll
        for (int ct = 0; ct < 4; ++ct)
#pragma unroll
          for (int r = 0; r < 16; ++r) {
            int q = qt * 32 + (r & 3) + 8 * (r >> 2) + 4 * l5;
            int cc = ct * 32 + l31;
            if (wv == 0) lds_o[q * 128 + cc] = oacc[qt][ct][r];
            else         lds_o[q * 128 + cc] += oacc[qt][ct][r];
          }
    }
    __syncthreads();
  }

  // ---- epilogue: out = x + gamma * O / l ----
  const int q = t >> 2;
  const float linv = 1.0f / (((lds_l[q] + lds_l[64 + q]) + (lds_l[128 + q] + lds_l[192 + q])));
  const size_t rowbase = ((size_t)(b * 4096 + q0 + q) << 9) + vc0;
#pragma unroll
  for (int ii = 0; ii < 8; ++ii) {
    int cc = ii * 16 + (t & 3) * 4;
    f32x4 o = *(const f32x4*)&lds_o[q * 128 + cc];
    f32x4 xr = *(const f32x4*)(x + rowbase + cc);
    f32x4 res;
#pragma unroll
    for (int r = 0; r < 4; ++r) res[r] = xr[r] + gamma * o[r] * linv;
    *(f32x4*)(out + rowbase + cc) = res;
  }
}

extern "C" void kernel_launch(void* const* d_in, const int* in_sizes, int n_in,
                              void* d_out, int out_size, void* d_ws, size_t ws_size,
                              hipStream_t stream) {
  const float* x   = (const float*)d_in[0];
  const float* Wf  = (const float*)d_in[1];
  const float* bfv = (const float*)d_in[2];
  const float* Wg  = (const float*)d_in[3];
  const float* bgv = (const float*)d_in[4];
  const float* Wh  = (const float*)d_in[5];
  const float* bhv = (const float*)d_in[6];
  const float* gam = (const float*)d_in[7];
  float* out = (float*)d_out;

  char* ws = (char*)d_ws;                  // total scratch: ~21.6 MB
  u16*   Wt    = (u16*)(ws);               // 640*512*2   = 655360
  float* biasc = (float*)(ws + 655360);    // 640*4       = 2560
  u16*   fo    = (u16*)(ws + 657920);      // 16384*64*2  = 2097152
  u16*   go    = (u16*)(ws + 2755072);     // 2097152
  u16*   ht    = (u16*)(ws + 4852224);     // 4*512*4096*2 = 16777216

  pack_weights2<<<80, 256, 0, stream>>>(Wf, Wg, Wh, bfv, bgv, bhv, Wt, biasc);
  proj_gemm2<<<dim3(256, 5), 256, 0, stream>>>(x, Wt, biasc, fo, go, ht);
  attn4<<<1024, 256, 0, stream>>>((const f16*)fo, (const f16*)go, (const f16*)ht, x, gam, out);
}

// Round 6
// 262.809 us; speedup vs baseline: 1.1450x; 1.1450x over previous
//
#include <hip/hip_runtime.h>
#include <stdint.h>

typedef uint16_t u16;
typedef _Float16 f16;
typedef __attribute__((ext_vector_type(8)))  f16      f16x8;
typedef __attribute__((ext_vector_type(8)))  uint16_t u16x8;
typedef __attribute__((ext_vector_type(4)))  uint16_t u16x4;
typedef __attribute__((ext_vector_type(4)))  float    f32x4;

#define LOG2E 1.44269504088896340736f
#define MFMA16F(a, b, c) __builtin_amdgcn_mfma_f32_16x16x32_f16((a), (b), (c), 0, 0, 0)

__device__ __forceinline__ u16 f2h(float f) {
  f16 h = (f16)f;
  return __builtin_bit_cast(u16, h);
}

// LDS tiles: [rows][64 f16] = 8 chunks of 16B per row, chunk XOR-swizzled by row&7.
__device__ __forceinline__ f16x8 ldsFrag(const u16* base, int row, int chunk) {
  const u16* p = base + row * 64 + ((chunk ^ (row & 7)) << 3);
  u16x8 raw = *(const u16x8*)p;
  return __builtin_bit_cast(f16x8, raw);
}
__device__ __forceinline__ void ldsPut(u16* base, int row, int logicalChunk, u16x8 v) {
  u16* p = base + row * 64 + ((logicalChunk ^ (row & 7)) << 3);
  *(u16x8*)p = v;
}

// async global->LDS DMA, 16B/lane; LDS dest = wave-uniform base + lane*16.
__device__ __forceinline__ void dma16(const u16* g, u16* l) {
  __builtin_amdgcn_global_load_lds(
      (const __attribute__((address_space(1))) uint32_t*)g,
      (__attribute__((address_space(3))) uint32_t*)l, 16, 0, 0);
}

// ---------------- kernel 0: pack weights ----------------
// Wt[n][k] f16 (n<64: Wf*log2e, n<128: Wg, else Wh), biasc[n] fp32 (bf*log2e).
__global__ __launch_bounds__(256) void pack_weights2(
    const float* __restrict__ Wf, const float* __restrict__ Wg,
    const float* __restrict__ Wh, const float* __restrict__ bfv,
    const float* __restrict__ bgv, const float* __restrict__ bhv,
    u16* __restrict__ Wt, float* __restrict__ biasc) {
  __shared__ u16 T[64 * 64];       // [k][n]
  const int nt = blockIdx.x >> 3;  // 0..9
  const int kt = blockIdx.x & 7;   // 0..7
  const int n0 = nt * 64, k0 = kt * 64;
  const float* src; int stride, cbase; float scale = 1.0f;
  if (nt == 0)      { src = Wf; stride = 64;  cbase = 0;        scale = LOG2E; }
  else if (nt == 1) { src = Wg; stride = 64;  cbase = 0; }
  else              { src = Wh; stride = 512; cbase = n0 - 128; }
  const int t = threadIdx.x;
  const int cl = (t & 15) * 4, r0 = t >> 4;
#pragma unroll
  for (int j = 0; j < 4; ++j) {
    int r = r0 + j * 16;
    f32x4 v = *(const f32x4*)(src + (size_t)(k0 + r) * stride + cbase + cl);
    u16x4 o;
#pragma unroll
    for (int i = 0; i < 4; ++i) o[i] = f2h(v[i] * scale);
    *(u16x4*)(T + r * 64 + cl) = o;
  }
  __syncthreads();
  const int n = t >> 2, kq = (t & 3) * 16;
  u16x8 a, b2;
#pragma unroll
  for (int i = 0; i < 8; ++i) { a[i] = T[(kq + i) * 64 + n]; b2[i] = T[(kq + 8 + i) * 64 + n]; }
  *(u16x8*)(Wt + (size_t)(n0 + n) * 512 + k0 + kq) = a;
  *(u16x8*)(Wt + (size_t)(n0 + n) * 512 + k0 + kq + 8) = b2;
  if (kt == 0 && t < 64) {
    float bv = (nt == 0) ? bfv[t] * LOG2E : (nt == 1) ? bgv[t] : bhv[cbase + t];
    biasc[n0 + t] = bv;
  }
}

// ---------------- kernel 1: projection GEMM (M=64, N=128, 1280 blocks) -------
__global__ __launch_bounds__(256, 4) void proj_gemm2(
    const float* __restrict__ x, const u16* __restrict__ Wt,
    const float* __restrict__ biasc,
    u16* __restrict__ fo, u16* __restrict__ go, u16* __restrict__ ht) {
  __shared__ u16 smem[64 * 64 + 128 * 64];   // 24 KB: A | B, reused as T
  u16* lds_a = smem;
  u16* lds_b = smem + 64 * 64;
  const int t = threadIdx.x, lane = t & 63, w = t >> 6;
  const int m0 = blockIdx.x * 64, n0 = blockIdx.y * 128;
  const int l15 = lane & 15, l4 = lane >> 4;
  const int sr = t >> 3, sc = t & 7;
  const int dmarow = lane >> 3, dmachunk = (lane & 7) ^ (lane >> 3);

  f32x4 acc[4][2];
#pragma unroll
  for (int i = 0; i < 4; ++i)
#pragma unroll
    for (int j = 0; j < 2; ++j) acc[i][j] = (f32x4)(0.f);

  for (int kb = 0; kb < 8; ++kb) {
    const int k0 = kb * 64;
    if (kb) __syncthreads();
#pragma unroll
    for (int p = 0; p < 2; ++p) {            // stage A: x fp32 -> f16 (64x64)
      int rr = p * 32 + sr;
      const float* s = x + (size_t)(m0 + rr) * 512 + k0 + sc * 8;
      f32x4 a0 = *(const f32x4*)s;
      f32x4 a1 = *(const f32x4*)(s + 4);
      u16x8 v;
#pragma unroll
      for (int i = 0; i < 4; ++i) { v[i] = f2h(a0[i]); v[4 + i] = f2h(a1[i]); }
      ldsPut(lds_a, rr, sc, v);
    }
#pragma unroll
    for (int ii = 0; ii < 4; ++ii) {         // stage B: Wt via DMA (128x64)
      int rw = w * 32 + ii * 8;
      const u16* src = Wt + (size_t)(n0 + rw + dmarow) * 512 + k0 + dmachunk * 8;
      dma16(src, lds_b + rw * 64);
    }
    __syncthreads();
#pragma unroll
    for (int ks = 0; ks < 2; ++ks) {
      const int chunk = ks * 4 + l4;
      f16x8 af[4], bq[2];
#pragma unroll
      for (int mt = 0; mt < 4; ++mt) af[mt] = ldsFrag(lds_a, mt * 16 + l15, chunk);
#pragma unroll
      for (int nt = 0; nt < 2; ++nt) bq[nt] = ldsFrag(lds_b, w * 32 + nt * 16 + l15, chunk);
#pragma unroll
      for (int mt = 0; mt < 4; ++mt)
#pragma unroll
        for (int nt = 0; nt < 2; ++nt) acc[mt][nt] = MFMA16F(af[mt], bq[nt], acc[mt][nt]);
    }
  }

  if (n0 >= 128) {
    // ---- h path: LDS-bounce transpose -> coalesced ht stores ----
    __syncthreads();
#pragma unroll
    for (int nt = 0; nt < 2; ++nt) {
      int nl = w * 32 + nt * 16 + l15;       // n within block (0..127)
      float bv = biasc[n0 + nl];
#pragma unroll
      for (int mt = 0; mt < 4; ++mt) {
        int mb = mt * 16 + (l4 << 2);
        f32x4 a = acc[mt][nt];
        u16x4 v;
#pragma unroll
        for (int r = 0; r < 4; ++r) v[r] = f2h(a[r] + bv);
        u16* dst = smem + nl * 64 + (((mb >> 3) ^ (nl & 7)) << 3) + (mb & 7);
        *(u16x4*)dst = v;
      }
    }
    __syncthreads();
    const int bb = m0 >> 12, posb = m0 & 4095;
    const int rr = t >> 1, half = t & 1;
    int vcol = n0 - 128 + rr;
#pragma unroll
    for (int j = 0; j < 4; ++j) {
      int ch = half * 4 + j;
      u16x8 v = *(const u16x8*)(smem + rr * 64 + ((ch ^ (rr & 7)) << 3));
      *(u16x8*)(ht + ((size_t)(bb * 512 + vcol) << 12) + posb + ch * 8) = v;
    }
  } else {
    // ---- f/g path ----
#pragma unroll
    for (int nt = 0; nt < 2; ++nt) {
      int n = w * 32 + nt * 16 + l15;
      float bv = biasc[n];
#pragma unroll
      for (int mt = 0; mt < 4; ++mt) {
        int mrow = m0 + mt * 16 + (l4 << 2);
        f32x4 a = acc[mt][nt];
        if (n < 64) {
#pragma unroll
          for (int r = 0; r < 4; ++r) fo[(size_t)(mrow + r) * 64 + n] = f2h(a[r] + bv);
        } else {
#pragma unroll
          for (int r = 0; r < 4; ++r) go[(size_t)(mrow + r) * 64 + (n - 64)] = f2h(a[r] + bv);
        }
      }
    }
  }
}

// ---------------- kernel 2: attention v5 ----------------
// 512 blocks x 4 waves (2 blocks/CU). Block: Q=64 q x VC=256 c, Kt=64 keys/iter.
// Slice swizzle i&7 -> (batch, c-half): one 2 MB ht slice per XCD, L2-resident.
// S^T = g.f^T with g A-frags DIRECT from L2 (no LDS staging); P via
// double-buffered LDS -> ONE barrier/iter. ht(k) B-frags loaded pre-barrier
// (barrier's vmcnt drain = free prefetch); g(k+1) issued during PV(k).
// No O replication: wave owns 64 c, P read from LDS by all 4 waves.
__global__ __launch_bounds__(256, 2) void attn5(
    const f16* __restrict__ fq, const f16* __restrict__ gk,
    const f16* __restrict__ ht, const float* __restrict__ x,
    const float* __restrict__ gamma_p, float* __restrict__ out) {
  __shared__ u16 lds_p[2][64 * 64];    // P dbuf, swizzled [q][key]
  __shared__ float lds_red[4 * 64];
  __shared__ float lds_linv[64];

  const int i = blockIdx.x;            // 512 blocks
  const int slice = i & 7;             // XCD-aligned
  const int b = slice >> 1, vq = slice & 1;
  const int qb = i >> 3;               // 0..63
  const int q0 = qb * 64, vc0 = vq * 256;

  const int t = threadIdx.x, lane = t & 63, w = t >> 6;
  const int l15 = lane & 15, l4 = lane >> 4;
  const float gamma = gamma_p[0];

  // per-lane base pointers
  const f16* gkb = gk + ((size_t)(b * 4096) + w * 16 + l15) * 64 + l4 * 8;
  const f16* htw = ht + ((size_t)(b * 512 + vc0 + w * 64 + l15)) * 4096 + l4 * 8;

  // f B-frags (S^T): all 64 q of this block, pinned in regs
  f16x8 fB[4][2];
#pragma unroll
  for (int qt = 0; qt < 4; ++qt)
#pragma unroll
    for (int ks = 0; ks < 2; ++ks)
      fB[qt][ks] = *(const f16x8*)(fq + (size_t)(b * 4096 + q0 + qt * 16 + l15) * 64 + ks * 32 + l4 * 8);

  f32x4 oacc[4][4];
#pragma unroll
  for (int qt = 0; qt < 4; ++qt)
#pragma unroll
    for (int ct = 0; ct < 4; ++ct) oacc[qt][ct] = (f32x4)(0.f);
  float lrun[4] = {0.f, 0.f, 0.f, 0.f};

  // prologue: g(0) A-frags direct from L2
  f16x8 gA[2];
  gA[0] = *(const f16x8*)(gkb);
  gA[1] = *(const f16x8*)(gkb + 32);

  for (int kt = 0; kt < 64; ++kt) {
    const int k0 = kt * 64;
    u16* pbuf = lds_p[kt & 1];
    // ---- S^T: this wave's 16 keys x all 64 q ----
    f32x4 sacc[4];
#pragma unroll
    for (int qt = 0; qt < 4; ++qt) sacc[qt] = (f32x4)(0.f);
#pragma unroll
    for (int ks = 0; ks < 2; ++ks)
#pragma unroll
      for (int qt = 0; qt < 4; ++qt) sacc[qt] = MFMA16F(gA[ks], fB[qt][ks], sacc[qt]);
    // issue ht(kt) B-frag loads now; barrier's vmcnt drain covers the latency
    f16x8 hb[2][4];
#pragma unroll
    for (int ks = 0; ks < 2; ++ks)
#pragma unroll
      for (int ct = 0; ct < 4; ++ct)
        hb[ks][ct] = *(const f16x8*)(htw + (size_t)(ct * 16) * 4096 + k0 + ks * 32);
    // exp2 (log2e pre-folded; -12 shift keeps P in f16 range), P-write, l partials
#pragma unroll
    for (int qt = 0; qt < 4; ++qt) {
      f32x4 s = sacc[qt];
      f32x4 p;
#pragma unroll
      for (int r = 0; r < 4; ++r) p[r] = __builtin_amdgcn_exp2f(s[r] - 12.0f);
      lrun[qt] += (p[0] + p[1]) + (p[2] + p[3]);
      u16x4 pb;
#pragma unroll
      for (int r = 0; r < 4; ++r) pb[r] = f2h(p[r]);
      int row = qt * 16 + l15;                 // q
      int keyb = w * 16 + (l4 << 2);           // 4 consecutive keys
      *(u16x4*)(pbuf + row * 64 + (((keyb >> 3) ^ (row & 7)) << 3) + (keyb & 7)) = pb;
    }
    __syncthreads();                           // ONE barrier/iter (P dbuf)
    // prefetch g(kt+1) — consumed next iter, no barrier in between
    if (kt < 63) {
      gA[0] = *(const f16x8*)(gkb + (size_t)(k0 + 64) * 64);
      gA[1] = *(const f16x8*)(gkb + (size_t)(k0 + 64) * 64 + 32);
    }
    // ---- PV: O[64q][64c per wave] += P . ht ----
#pragma unroll
    for (int ks = 0; ks < 2; ++ks) {
#pragma unroll
      for (int qt = 0; qt < 4; ++qt) {
        f16x8 pf = ldsFrag(pbuf, qt * 16 + l15, ks * 4 + l4);
#pragma unroll
        for (int ct = 0; ct < 4; ++ct)
          oacc[qt][ct] = MFMA16F(pf, hb[ks][ct], oacc[qt][ct]);
      }
    }
  }

  // ---- row-sum reduction across l4-groups and waves ----
#pragma unroll
  for (int qt = 0; qt < 4; ++qt) {
    lrun[qt] += __shfl_xor(lrun[qt], 16);
    lrun[qt] += __shfl_xor(lrun[qt], 32);
  }
  if (l4 == 0) {
#pragma unroll
    for (int qt = 0; qt < 4; ++qt) lds_red[w * 64 + qt * 16 + l15] = lrun[qt];
  }
  __syncthreads();
  if (t < 64) {
    float s = (lds_red[t] + lds_red[64 + t]) + (lds_red[128 + t] + lds_red[192 + t]);
    lds_linv[t] = gamma / s;                   // fold gamma into 1/l
  }
  __syncthreads();

  // ---- epilogue: out = x + O * (gamma/l) ----
#pragma unroll
  for (int qt = 0; qt < 4; ++qt) {
    f32x4 linv = *(const f32x4*)&lds_linv[qt * 16 + (l4 << 2)];
#pragma unroll
    for (int ct = 0; ct < 4; ++ct) {
      int c = vc0 + w * 64 + ct * 16 + l15;
#pragma unroll
      for (int r = 0; r < 4; ++r) {
        int q = q0 + qt * 16 + (l4 << 2) + r;
        size_t idx = ((size_t)(b * 4096 + q) << 9) + c;
        out[idx] = x[idx] + oacc[qt][ct][r] * linv[r];
      }
    }
  }
}

extern "C" void kernel_launch(void* const* d_in, const int* in_sizes, int n_in,
                              void* d_out, int out_size, void* d_ws, size_t ws_size,
                              hipStream_t stream) {
  const float* x   = (const float*)d_in[0];
  const float* Wf  = (const float*)d_in[1];
  const float* bfv = (const float*)d_in[2];
  const float* Wg  = (const float*)d_in[3];
  const float* bgv = (const float*)d_in[4];
  const float* Wh  = (const float*)d_in[5];
  const float* bhv = (const float*)d_in[6];
  const float* gam = (const float*)d_in[7];
  float* out = (float*)d_out;

  char* ws = (char*)d_ws;                  // total scratch: ~21.6 MB
  u16*   Wt    = (u16*)(ws);               // 640*512*2   = 655360
  float* biasc = (float*)(ws + 655360);    // 640*4       = 2560
  u16*   fo    = (u16*)(ws + 657920);      // 16384*64*2  = 2097152
  u16*   go    = (u16*)(ws + 2755072);     // 2097152
  u16*   ht    = (u16*)(ws + 4852224);     // 4*512*4096*2 = 16777216

  pack_weights2<<<80, 256, 0, stream>>>(Wf, Wg, Wh, bfv, bgv, bhv, Wt, biasc);
  proj_gemm2<<<dim3(256, 5), 256, 0, stream>>>(x, Wt, biasc, fo, go, ht);
  attn5<<<512, 256, 0, stream>>>((const f16*)fo, (const f16*)go, (const f16*)ht, x, gam, out);
}